// Round 1
// baseline (1536.259 us; speedup 1.0000x reference)
//
#include <hip/hip_runtime.h>
#include <hip/hip_bf16.h>

using bf16x8 = __attribute__((ext_vector_type(8))) short;
using f32x4  = __attribute__((ext_vector_type(4))) float;

#define NTOK 8192
#define DDIM 1024
#define NEXP 8
#define HDIM 4096
#define CAP  17408   // 16384 pairs + 8*128 padding
#define MT   136     // CAP / 128 M-tiles (worst case)

struct Ctrl {
  unsigned cnt[8];
  unsigned cursor[8];
  unsigned off[9];
  unsigned used_end;
  float imp[8];
  float loadsum[8];
  float validcnt;
};

__device__ inline unsigned short f2bfu(float f) {
  __hip_bfloat16 h = __float2bfloat16(f);
  return *reinterpret_cast<unsigned short*>(&h);
}
__device__ inline bf16x8 cvt8(float4 a, float4 b) {
  bf16x8 v;
  v[0] = (short)f2bfu(a.x); v[1] = (short)f2bfu(a.y);
  v[2] = (short)f2bfu(a.z); v[3] = (short)f2bfu(a.w);
  v[4] = (short)f2bfu(b.x); v[5] = (short)f2bfu(b.y);
  v[6] = (short)f2bfu(b.z); v[7] = (short)f2bfu(b.w);
  return v;
}

// ---------------- Router: logits -> softmax -> top2 -> stats ----------------
__global__ __launch_bounds__(256) void router_kernel(
    const float* __restrict__ x, const int* __restrict__ mask,
    const float* __restrict__ rw, Ctrl* __restrict__ ctrl,
    int* __restrict__ top2i, float* __restrict__ top2w)
{
  __shared__ float srw[NEXP * DDIM];
  for (int i = threadIdx.x; i < NEXP * DDIM; i += 256) srw[i] = rw[i];
  __syncthreads();

  int wid = threadIdx.x >> 6, lane = threadIdx.x & 63;
  int token = blockIdx.x * 4 + wid;

  const float* xr = x + (size_t)token * DDIM + lane * 16;
  float xs[16];
  #pragma unroll
  for (int i = 0; i < 16; i += 4) *(float4*)&xs[i] = *(const float4*)(xr + i);

  float s[8];
  #pragma unroll
  for (int e = 0; e < 8; ++e) {
    const float* rp = &srw[e * DDIM + lane * 16];
    float a = 0.f;
    #pragma unroll
    for (int i = 0; i < 16; ++i) a += xs[i] * rp[i];
    s[e] = a;
  }
  #pragma unroll
  for (int e = 0; e < 8; ++e)
    for (int o = 32; o; o >>= 1) s[e] += __shfl_xor(s[e], o);

  if (lane == 0) {
    int m = mask[token];
    float mx = s[0];
    #pragma unroll
    for (int e = 1; e < 8; ++e) mx = fmaxf(mx, s[e]);
    float p[8], sum = 0.f;
    #pragma unroll
    for (int e = 0; e < 8; ++e) { p[e] = __expf(s[e] - mx); sum += p[e]; }
    float inv = 1.0f / sum;
    #pragma unroll
    for (int e = 0; e < 8; ++e) p[e] *= inv;
    int i1 = 0;
    #pragma unroll
    for (int e = 1; e < 8; ++e) if (p[e] > p[i1]) i1 = e;
    int i2 = (i1 == 0) ? 1 : 0;
    #pragma unroll
    for (int e = 0; e < 8; ++e) if (e != i1 && p[e] > p[i2]) i2 = e;
    float denom = p[i1] + p[i2] + 1e-9f;
    top2i[2 * token] = i1;       top2i[2 * token + 1] = i2;
    top2w[2 * token] = p[i1] / denom; top2w[2 * token + 1] = p[i2] / denom;
    if (m) {
      #pragma unroll
      for (int e = 0; e < 8; ++e) atomicAdd(&ctrl->imp[e], p[e]);
      atomicAdd(&ctrl->loadsum[i1], 1.0f);
      atomicAdd(&ctrl->validcnt, 1.0f);
      atomicAdd(&ctrl->cnt[i1], 1u);
      atomicAdd(&ctrl->cnt[i2], 1u);
    }
  }
}

// ---------------- Offsets (128-aligned segments) + aux loss ----------------
__global__ void finalize_kernel(Ctrl* __restrict__ c, float* __restrict__ auxout)
{
  unsigned o = 0;
  for (int e = 0; e < 8; ++e) { c->off[e] = o; o += (c->cnt[e] + 127u) & ~127u; }
  c->off[8] = o;
  c->used_end = o;
  float cn = fmaxf(c->validcnt, 1.0f);
  float aux = 0.f;
  for (int e = 0; e < 8; ++e) aux += c->imp[e] * c->loadsum[e];
  auxout[0] = aux * 8.0f / (cn * cn);
}

// ---------------- Scatter pairs into per-expert segments ----------------
__global__ __launch_bounds__(256) void scatter_kernel(
    const int* __restrict__ mask, Ctrl* __restrict__ ctrl,
    const int* __restrict__ top2i, const float* __restrict__ top2w,
    int* __restrict__ ptok, float* __restrict__ pwv)
{
  int token = blockIdx.x * 256 + threadIdx.x;
  if (token >= NTOK) return;
  if (!mask[token]) return;
  #pragma unroll
  for (int k = 0; k < 2; ++k) {
    int e = top2i[2 * token + k];
    unsigned pos = atomicAdd(&ctrl->cursor[e], 1u);
    unsigned row = ctrl->off[e] + pos;
    ptok[row] = token;
    pwv[row] = top2w[2 * token + k];
  }
}

// ---------------- fc1: H = silu(Xgathered @ w1[e]^T + b1) -> bf16 ----------------
__global__ __launch_bounds__(256) void fc1_kernel(
    const float* __restrict__ x, const float* __restrict__ w1,
    const float* __restrict__ b1, const int* __restrict__ ptok,
    const Ctrl* __restrict__ ctrl, unsigned short* __restrict__ Hbuf,
    int halfoff, int hcols)
{
  __shared__ short As[2][4096];
  __shared__ short Bs[2][4096];

  int m0 = blockIdx.y * 128;
  if ((unsigned)m0 >= ctrl->used_end) return;
  int e = 0;
  #pragma unroll
  for (int i = 1; i < 8; ++i) if ((unsigned)m0 >= ctrl->off[i]) e = i;

  int n0 = blockIdx.x * 128;
  int t = threadIdx.x;
  int r = t >> 1, sg = t & 1;
  int tok = ptok[m0 + r];
  const float* aSrc = x + (size_t)(tok < 0 ? 0 : tok) * DDIM + sg * 16;
  const float* bSrc = w1 + ((size_t)e * HDIM + halfoff + n0 + r) * DDIM + sg * 16;

  int wrA = r * 32;
  int ca = ((sg * 2)     ^ (r & 3)) << 3;   // XOR-swizzled 16B chunk offsets
  int cb = ((sg * 2 + 1) ^ (r & 3)) << 3;

  int lane = t & 63, wid = t >> 6, wm = wid >> 1, wn = wid & 1;
  int kc = lane >> 4, rl = lane & 15;

  { // prologue stage kt=0 into buf0
    float4 a0, a1, a2, a3, b0, b1v, b2v, b3;
    const float4* ap = (const float4*)aSrc;
    const float4* bp = (const float4*)bSrc;
    if (tok >= 0) { a0 = ap[0]; a1 = ap[1]; a2 = ap[2]; a3 = ap[3]; }
    else { a0 = a1 = a2 = a3 = make_float4(0, 0, 0, 0); }
    b0 = bp[0]; b1v = bp[1]; b2v = bp[2]; b3 = bp[3];
    *(bf16x8*)&As[0][wrA + ca] = cvt8(a0, a1);
    *(bf16x8*)&As[0][wrA + cb] = cvt8(a2, a3);
    *(bf16x8*)&Bs[0][wrA + ca] = cvt8(b0, b1v);
    *(bf16x8*)&Bs[0][wrA + cb] = cvt8(b2v, b3);
  }
  __syncthreads();

  f32x4 acc[4][4] = {};
  const int NKL = DDIM / 32;
  for (int kt = 0; kt < NKL; ++kt) {
    int cur = kt & 1, nxt = cur ^ 1;
    bool more = (kt + 1) < NKL;
    float4 a0, a1, a2, a3, b0, b1v, b2v, b3;
    if (more) {
      const float4* ap = (const float4*)(aSrc + (kt + 1) * 32);
      const float4* bp = (const float4*)(bSrc + (kt + 1) * 32);
      if (tok >= 0) { a0 = ap[0]; a1 = ap[1]; a2 = ap[2]; a3 = ap[3]; }
      else { a0 = a1 = a2 = a3 = make_float4(0, 0, 0, 0); }
      b0 = bp[0]; b1v = bp[1]; b2v = bp[2]; b3 = bp[3];
    }
    bf16x8 af[4], bfr[4];
    #pragma unroll
    for (int mi = 0; mi < 4; ++mi) {
      int rr = wm * 64 + mi * 16 + rl;
      af[mi] = *(bf16x8*)&As[cur][rr * 32 + ((kc ^ (rr & 3)) << 3)];
    }
    #pragma unroll
    for (int ni = 0; ni < 4; ++ni) {
      int rr = wn * 64 + ni * 16 + rl;
      bfr[ni] = *(bf16x8*)&Bs[cur][rr * 32 + ((kc ^ (rr & 3)) << 3)];
    }
    #pragma unroll
    for (int mi = 0; mi < 4; ++mi)
      #pragma unroll
      for (int ni = 0; ni < 4; ++ni)
        acc[mi][ni] = __builtin_amdgcn_mfma_f32_16x16x32_bf16(af[mi], bfr[ni], acc[mi][ni], 0, 0, 0);
    if (more) {
      *(bf16x8*)&As[nxt][wrA + ca] = cvt8(a0, a1);
      *(bf16x8*)&As[nxt][wrA + cb] = cvt8(a2, a3);
      *(bf16x8*)&Bs[nxt][wrA + ca] = cvt8(b0, b1v);
      *(bf16x8*)&Bs[nxt][wrA + cb] = cvt8(b2v, b3);
    }
    __syncthreads();
  }

  // epilogue: bias + silu -> bf16 H
  #pragma unroll
  for (int mi = 0; mi < 4; ++mi) {
    #pragma unroll
    for (int rr2 = 0; rr2 < 4; ++rr2) {
      int grow = m0 + wm * 64 + mi * 16 + kc * 4 + rr2;
      size_t base = (size_t)grow * hcols;
      #pragma unroll
      for (int ni = 0; ni < 4; ++ni) {
        int col = n0 + wn * 64 + ni * 16 + rl;
        float v = acc[mi][ni][rr2] + b1[e * HDIM + halfoff + col];
        v = v / (1.0f + __expf(-v));
        Hbuf[base + col] = f2bfu(v);
      }
    }
  }
}

// ---------------- fc2: y += w * (H @ w2[e]^T + b2) ----------------
__global__ __launch_bounds__(256) void fc2_kernel(
    const unsigned short* __restrict__ Hbuf, const float* __restrict__ w2,
    const float* __restrict__ b2, const int* __restrict__ ptok,
    const float* __restrict__ pwv, const Ctrl* __restrict__ ctrl,
    float* __restrict__ y, int halfoff, int hcols)
{
  __shared__ short As[2][4096];
  __shared__ short Bs[2][4096];

  int m0 = blockIdx.y * 128;
  if ((unsigned)m0 >= ctrl->used_end) return;
  int e = 0;
  #pragma unroll
  for (int i = 1; i < 8; ++i) if ((unsigned)m0 >= ctrl->off[i]) e = i;

  int n0 = blockIdx.x * 128;   // within D
  int t = threadIdx.x;
  int r = t >> 1, sg = t & 1;
  const unsigned short* aSrc = Hbuf + (size_t)(m0 + r) * hcols + sg * 16;
  const float* bSrc = w2 + ((size_t)e * DDIM + n0 + r) * HDIM + halfoff + sg * 16;

  int wrA = r * 32;
  int ca = ((sg * 2)     ^ (r & 3)) << 3;
  int cb = ((sg * 2 + 1) ^ (r & 3)) << 3;

  int lane = t & 63, wid = t >> 6, wm = wid >> 1, wn = wid & 1;
  int kc = lane >> 4, rl = lane & 15;

  {
    const bf16x8* ap = (const bf16x8*)aSrc;
    const float4* bp = (const float4*)bSrc;
    bf16x8 a0 = ap[0], a1 = ap[1];
    float4 b0 = bp[0], b1v = bp[1], b2v = bp[2], b3 = bp[3];
    *(bf16x8*)&As[0][wrA + ca] = a0;
    *(bf16x8*)&As[0][wrA + cb] = a1;
    *(bf16x8*)&Bs[0][wrA + ca] = cvt8(b0, b1v);
    *(bf16x8*)&Bs[0][wrA + cb] = cvt8(b2v, b3);
  }
  __syncthreads();

  f32x4 acc[4][4] = {};
  const int NKL = hcols / 32;
  for (int kt = 0; kt < NKL; ++kt) {
    int cur = kt & 1, nxt = cur ^ 1;
    bool more = (kt + 1) < NKL;
    bf16x8 a0, a1;
    float4 b0, b1v, b2v, b3;
    if (more) {
      const bf16x8* ap = (const bf16x8*)(aSrc + (size_t)(kt + 1) * 32);
      const float4* bp = (const float4*)(bSrc + (kt + 1) * 32);
      a0 = ap[0]; a1 = ap[1];
      b0 = bp[0]; b1v = bp[1]; b2v = bp[2]; b3 = bp[3];
    }
    bf16x8 af[4], bfr[4];
    #pragma unroll
    for (int mi = 0; mi < 4; ++mi) {
      int rr = wm * 64 + mi * 16 + rl;
      af[mi] = *(bf16x8*)&As[cur][rr * 32 + ((kc ^ (rr & 3)) << 3)];
    }
    #pragma unroll
    for (int ni = 0; ni < 4; ++ni) {
      int rr = wn * 64 + ni * 16 + rl;
      bfr[ni] = *(bf16x8*)&Bs[cur][rr * 32 + ((kc ^ (rr & 3)) << 3)];
    }
    #pragma unroll
    for (int mi = 0; mi < 4; ++mi)
      #pragma unroll
      for (int ni = 0; ni < 4; ++ni)
        acc[mi][ni] = __builtin_amdgcn_mfma_f32_16x16x32_bf16(af[mi], bfr[ni], acc[mi][ni], 0, 0, 0);
    if (more) {
      *(bf16x8*)&As[nxt][wrA + ca] = a0;
      *(bf16x8*)&As[nxt][wrA + cb] = a1;
      *(bf16x8*)&Bs[nxt][wrA + ca] = cvt8(b0, b1v);
      *(bf16x8*)&Bs[nxt][wrA + cb] = cvt8(b2v, b3);
    }
    __syncthreads();
  }

  // epilogue: (+b2 on first chunk) * combine-weight, scatter-add into y
  #pragma unroll
  for (int mi = 0; mi < 4; ++mi) {
    #pragma unroll
    for (int rr2 = 0; rr2 < 4; ++rr2) {
      int grow = m0 + wm * 64 + mi * 16 + kc * 4 + rr2;
      int tok = ptok[grow];
      if (tok < 0) continue;
      float wgt = pwv[grow];
      float* yrow = y + (size_t)tok * DDIM;
      #pragma unroll
      for (int ni = 0; ni < 4; ++ni) {
        int col = n0 + wn * 64 + ni * 16 + rl;
        float v = acc[mi][ni][rr2];
        if (halfoff == 0) v += b2[e * DDIM + col];
        atomicAdd(&yrow[col], wgt * v);
      }
    }
  }
}

extern "C" void kernel_launch(void* const* d_in, const int* in_sizes, int n_in,
                              void* d_out, int out_size, void* d_ws, size_t ws_size,
                              hipStream_t stream) {
  (void)in_sizes; (void)n_in;
  const float* xp   = (const float*)d_in[0];
  const int*   mkp  = (const int*)d_in[1];
  const float* rwp  = (const float*)d_in[2];
  const float* w1p  = (const float*)d_in[3];
  const float* b1p  = (const float*)d_in[4];
  const float* w2p  = (const float*)d_in[5];
  const float* b2p  = (const float*)d_in[6];

  float* yp   = (float*)d_out;
  float* auxp = (float*)d_out + (out_size - 1);

  char* wsb = (char*)d_ws;
  Ctrl* ctrl = (Ctrl*)wsb;
  int*   top2i = (int*)(wsb + 1024);
  float* top2w = (float*)(wsb + 1024 + 65536);
  int*   ptok  = (int*)(wsb + 1024 + 131072);
  float* pwv   = (float*)(wsb + 1024 + 131072 + 69632);
  unsigned short* Hbuf = (unsigned short*)(wsb + 1048576);

  // choose H-chunk width so the bf16 H buffer fits the workspace (deterministic)
  int hcols = 4096;
  while (hcols > 128 && ws_size < 1048576 + (size_t)CAP * (size_t)hcols * 2) hcols >>= 1;
  int nchunks = HDIM / hcols;

  hipMemsetAsync(d_out, 0, (size_t)out_size * sizeof(float), stream);
  hipMemsetAsync(ctrl, 0, 256, stream);
  hipMemsetAsync(ptok, 0xFF, CAP * sizeof(int), stream);

  router_kernel<<<NTOK / 4, 256, 0, stream>>>(xp, mkp, rwp, ctrl, top2i, top2w);
  finalize_kernel<<<1, 1, 0, stream>>>(ctrl, auxp);
  scatter_kernel<<<NTOK / 256, 256, 0, stream>>>(mkp, ctrl, top2i, top2w, ptok, pwv);

  for (int c = 0; c < nchunks; ++c) {
    int hoff = c * hcols;
    fc1_kernel<<<dim3(hcols / 128, MT), 256, 0, stream>>>(xp, w1p, b1p, ptok, ctrl, Hbuf, hoff, hcols);
    fc2_kernel<<<dim3(DDIM / 128, MT), 256, 0, stream>>>(Hbuf, w2p, b2p, ptok, pwv, ctrl, yp, hoff, hcols);
  }
}

// Round 2
// 788.866 us; speedup vs baseline: 1.9474x; 1.9474x over previous
//
#include <hip/hip_runtime.h>
#include <hip/hip_bf16.h>

using bf16x8 = __attribute__((ext_vector_type(8))) short;
using f32x4  = __attribute__((ext_vector_type(4))) float;

#define NTOK 8192
#define DDIM 1024
#define NEXP 8
#define HDIM 4096
#define CAP  17408   // 16384 pairs + 8*128 padding
#define MT   136     // CAP / 128 M-tiles (worst case)

struct Ctrl {
  unsigned cnt[8];
  unsigned cursor[8];
  unsigned off[9];
  unsigned used_end;
  float imp[8];
  float loadsum[8];
  float validcnt;
};

__device__ inline unsigned short f2bfu(float f) {
  __hip_bfloat16 h = __float2bfloat16(f);
  return *reinterpret_cast<unsigned short*>(&h);
}
__device__ inline bf16x8 cvt8(float4 a, float4 b) {
  bf16x8 v;
  v[0] = (short)f2bfu(a.x); v[1] = (short)f2bfu(a.y);
  v[2] = (short)f2bfu(a.z); v[3] = (short)f2bfu(a.w);
  v[4] = (short)f2bfu(b.x); v[5] = (short)f2bfu(b.y);
  v[6] = (short)f2bfu(b.z); v[7] = (short)f2bfu(b.w);
  return v;
}

// ---------------- Router: logits -> softmax -> top2 -> stats ----------------
// 256 grid-strided blocks; stats accumulate in LDS, one global atomic per
// expert per block (was: 11 same-address global atomics PER TOKEN = 690us).
// router_w read directly from global (L1/L2-resident, coalesced) — the LDS
// copy had a 32-way bank conflict (lane stride 64B).
__global__ __launch_bounds__(256) void router_kernel(
    const float* __restrict__ x, const int* __restrict__ mask,
    const float* __restrict__ rw, Ctrl* __restrict__ ctrl,
    int* __restrict__ top2i, float* __restrict__ top2w)
{
  __shared__ float s_imp[8];
  __shared__ float s_load[8];
  __shared__ unsigned s_cnt[8];
  __shared__ unsigned s_valid;
  if (threadIdx.x < 8) { s_imp[threadIdx.x] = 0.f; s_load[threadIdx.x] = 0.f; s_cnt[threadIdx.x] = 0u; }
  if (threadIdx.x == 0) s_valid = 0u;
  __syncthreads();

  int wid = threadIdx.x >> 6, lane = threadIdx.x & 63;

  for (int token = blockIdx.x * 4 + wid; token < NTOK; token += gridDim.x * 4) {
    const float* xr = x + (size_t)token * DDIM + lane * 16;
    float4 x0 = ((const float4*)xr)[0];
    float4 x1 = ((const float4*)xr)[1];
    float4 x2 = ((const float4*)xr)[2];
    float4 x3 = ((const float4*)xr)[3];

    float s[8];
    #pragma unroll
    for (int e = 0; e < 8; ++e) {
      const float* rp = rw + e * DDIM + lane * 16;
      float4 r0 = ((const float4*)rp)[0];
      float4 r1 = ((const float4*)rp)[1];
      float4 r2 = ((const float4*)rp)[2];
      float4 r3 = ((const float4*)rp)[3];
      float a = x0.x * r0.x;
      a = fmaf(x0.y, r0.y, a); a = fmaf(x0.z, r0.z, a); a = fmaf(x0.w, r0.w, a);
      a = fmaf(x1.x, r1.x, a); a = fmaf(x1.y, r1.y, a); a = fmaf(x1.z, r1.z, a); a = fmaf(x1.w, r1.w, a);
      a = fmaf(x2.x, r2.x, a); a = fmaf(x2.y, r2.y, a); a = fmaf(x2.z, r2.z, a); a = fmaf(x2.w, r2.w, a);
      a = fmaf(x3.x, r3.x, a); a = fmaf(x3.y, r3.y, a); a = fmaf(x3.z, r3.z, a); a = fmaf(x3.w, r3.w, a);
      s[e] = a;
    }
    #pragma unroll
    for (int e = 0; e < 8; ++e)
      #pragma unroll
      for (int o = 32; o; o >>= 1) s[e] += __shfl_xor(s[e], o);

    if (lane == 0) {
      float mx = s[0];
      #pragma unroll
      for (int e = 1; e < 8; ++e) mx = fmaxf(mx, s[e]);
      float p[8], sum = 0.f;
      #pragma unroll
      for (int e = 0; e < 8; ++e) { p[e] = __expf(s[e] - mx); sum += p[e]; }
      float inv = 1.0f / sum;
      #pragma unroll
      for (int e = 0; e < 8; ++e) p[e] *= inv;
      int i1 = 0;
      #pragma unroll
      for (int e = 1; e < 8; ++e) if (p[e] > p[i1]) i1 = e;
      int i2 = (i1 == 0) ? 1 : 0;
      #pragma unroll
      for (int e = 0; e < 8; ++e) if (e != i1 && p[e] > p[i2]) i2 = e;
      float denom = p[i1] + p[i2] + 1e-9f;
      top2i[2 * token] = i1;            top2i[2 * token + 1] = i2;
      top2w[2 * token] = p[i1] / denom; top2w[2 * token + 1] = p[i2] / denom;
      if (mask[token]) {
        #pragma unroll
        for (int e = 0; e < 8; ++e) atomicAdd(&s_imp[e], p[e]);   // LDS atomics
        atomicAdd(&s_load[i1], 1.0f);
        atomicAdd(&s_cnt[i1], 1u);
        atomicAdd(&s_cnt[i2], 1u);
        atomicAdd(&s_valid, 1u);
      }
    }
  }
  __syncthreads();
  if (threadIdx.x < 8) {
    if (s_imp[threadIdx.x] != 0.f)  atomicAdd(&ctrl->imp[threadIdx.x], s_imp[threadIdx.x]);
    if (s_load[threadIdx.x] != 0.f) atomicAdd(&ctrl->loadsum[threadIdx.x], s_load[threadIdx.x]);
    if (s_cnt[threadIdx.x])         atomicAdd(&ctrl->cnt[threadIdx.x], s_cnt[threadIdx.x]);
  }
  if (threadIdx.x == 0 && s_valid) atomicAdd(&ctrl->validcnt, (float)s_valid);
}

// ---------------- Offsets (128-aligned segments) + aux loss ----------------
__global__ void finalize_kernel(Ctrl* __restrict__ c, float* __restrict__ auxout)
{
  unsigned o = 0;
  for (int e = 0; e < 8; ++e) { c->off[e] = o; o += (c->cnt[e] + 127u) & ~127u; }
  c->off[8] = o;
  c->used_end = o;
  float cn = fmaxf(c->validcnt, 1.0f);
  float aux = 0.f;
  for (int e = 0; e < 8; ++e) aux += c->imp[e] * c->loadsum[e];
  auxout[0] = aux * 8.0f / (cn * cn);
}

// ---------------- Scatter pairs into per-expert segments ----------------
// Block-local counts in LDS, one range-reservation atomic per expert per
// block, then LDS-cursor placement.
__global__ __launch_bounds__(256) void scatter_kernel(
    const int* __restrict__ mask, Ctrl* __restrict__ ctrl,
    const int* __restrict__ top2i, const float* __restrict__ top2w,
    int* __restrict__ ptok, float* __restrict__ pwv)
{
  __shared__ unsigned s_cnt[8], s_base[8], s_cur[8];
  if (threadIdx.x < 8) { s_cnt[threadIdx.x] = 0u; s_cur[threadIdx.x] = 0u; }
  __syncthreads();

  int token = blockIdx.x * 256 + threadIdx.x;
  int e0 = -1, e1 = -1; float w0 = 0.f, w1v = 0.f;
  bool valid = (token < NTOK) && mask[token];
  if (valid) {
    e0 = top2i[2 * token];     w0  = top2w[2 * token];
    e1 = top2i[2 * token + 1]; w1v = top2w[2 * token + 1];
    atomicAdd(&s_cnt[e0], 1u);
    atomicAdd(&s_cnt[e1], 1u);
  }
  __syncthreads();
  if (threadIdx.x < 8 && s_cnt[threadIdx.x])
    s_base[threadIdx.x] = ctrl->off[threadIdx.x] +
                          atomicAdd(&ctrl->cursor[threadIdx.x], s_cnt[threadIdx.x]);
  __syncthreads();
  if (valid) {
    unsigned p0 = atomicAdd(&s_cur[e0], 1u);
    unsigned row0 = s_base[e0] + p0;
    ptok[row0] = token; pwv[row0] = w0;
    unsigned p1 = atomicAdd(&s_cur[e1], 1u);
    unsigned row1 = s_base[e1] + p1;
    ptok[row1] = token; pwv[row1] = w1v;
  }
}

// ---------------- fc1: H = silu(Xgathered @ w1[e]^T + b1) -> bf16 ----------------
__global__ __launch_bounds__(256) void fc1_kernel(
    const float* __restrict__ x, const float* __restrict__ w1,
    const float* __restrict__ b1, const int* __restrict__ ptok,
    const Ctrl* __restrict__ ctrl, unsigned short* __restrict__ Hbuf,
    int halfoff, int hcols)
{
  __shared__ short As[2][4096];
  __shared__ short Bs[2][4096];

  int m0 = blockIdx.y * 128;
  if ((unsigned)m0 >= ctrl->used_end) return;
  int e = 0;
  #pragma unroll
  for (int i = 1; i < 8; ++i) if ((unsigned)m0 >= ctrl->off[i]) e = i;

  int n0 = blockIdx.x * 128;
  int t = threadIdx.x;
  int r = t >> 1, sg = t & 1;
  int tok = ptok[m0 + r];
  const float* aSrc = x + (size_t)(tok < 0 ? 0 : tok) * DDIM + sg * 16;
  const float* bSrc = w1 + ((size_t)e * HDIM + halfoff + n0 + r) * DDIM + sg * 16;

  int wrA = r * 32;
  int ca = ((sg * 2)     ^ (r & 3)) << 3;   // XOR-swizzled 16B chunk offsets
  int cb = ((sg * 2 + 1) ^ (r & 3)) << 3;

  int lane = t & 63, wid = t >> 6, wm = wid >> 1, wn = wid & 1;
  int kc = lane >> 4, rl = lane & 15;

  { // prologue stage kt=0 into buf0
    float4 a0, a1, a2, a3, b0, b1v, b2v, b3;
    const float4* ap = (const float4*)aSrc;
    const float4* bp = (const float4*)bSrc;
    if (tok >= 0) { a0 = ap[0]; a1 = ap[1]; a2 = ap[2]; a3 = ap[3]; }
    else { a0 = a1 = a2 = a3 = make_float4(0, 0, 0, 0); }
    b0 = bp[0]; b1v = bp[1]; b2v = bp[2]; b3 = bp[3];
    *(bf16x8*)&As[0][wrA + ca] = cvt8(a0, a1);
    *(bf16x8*)&As[0][wrA + cb] = cvt8(a2, a3);
    *(bf16x8*)&Bs[0][wrA + ca] = cvt8(b0, b1v);
    *(bf16x8*)&Bs[0][wrA + cb] = cvt8(b2v, b3);
  }
  __syncthreads();

  f32x4 acc[4][4] = {};
  const int NKL = DDIM / 32;
  for (int kt = 0; kt < NKL; ++kt) {
    int cur = kt & 1, nxt = cur ^ 1;
    bool more = (kt + 1) < NKL;
    float4 a0, a1, a2, a3, b0, b1v, b2v, b3;
    if (more) {
      const float4* ap = (const float4*)(aSrc + (kt + 1) * 32);
      const float4* bp = (const float4*)(bSrc + (kt + 1) * 32);
      if (tok >= 0) { a0 = ap[0]; a1 = ap[1]; a2 = ap[2]; a3 = ap[3]; }
      else { a0 = a1 = a2 = a3 = make_float4(0, 0, 0, 0); }
      b0 = bp[0]; b1v = bp[1]; b2v = bp[2]; b3 = bp[3];
    }
    bf16x8 af[4], bfr[4];
    #pragma unroll
    for (int mi = 0; mi < 4; ++mi) {
      int rr = wm * 64 + mi * 16 + rl;
      af[mi] = *(bf16x8*)&As[cur][rr * 32 + ((kc ^ (rr & 3)) << 3)];
    }
    #pragma unroll
    for (int ni = 0; ni < 4; ++ni) {
      int rr = wn * 64 + ni * 16 + rl;
      bfr[ni] = *(bf16x8*)&Bs[cur][rr * 32 + ((kc ^ (rr & 3)) << 3)];
    }
    #pragma unroll
    for (int mi = 0; mi < 4; ++mi)
      #pragma unroll
      for (int ni = 0; ni < 4; ++ni)
        acc[mi][ni] = __builtin_amdgcn_mfma_f32_16x16x32_bf16(af[mi], bfr[ni], acc[mi][ni], 0, 0, 0);
    if (more) {
      *(bf16x8*)&As[nxt][wrA + ca] = cvt8(a0, a1);
      *(bf16x8*)&As[nxt][wrA + cb] = cvt8(a2, a3);
      *(bf16x8*)&Bs[nxt][wrA + ca] = cvt8(b0, b1v);
      *(bf16x8*)&Bs[nxt][wrA + cb] = cvt8(b2v, b3);
    }
    __syncthreads();
  }

  // epilogue: bias + silu -> bf16 H
  #pragma unroll
  for (int mi = 0; mi < 4; ++mi) {
    #pragma unroll
    for (int rr2 = 0; rr2 < 4; ++rr2) {
      int grow = m0 + wm * 64 + mi * 16 + kc * 4 + rr2;
      size_t base = (size_t)grow * hcols;
      #pragma unroll
      for (int ni = 0; ni < 4; ++ni) {
        int col = n0 + wn * 64 + ni * 16 + rl;
        float v = acc[mi][ni][rr2] + b1[e * HDIM + halfoff + col];
        v = v / (1.0f + __expf(-v));
        Hbuf[base + col] = f2bfu(v);
      }
    }
  }
}

// ---------------- fc2: y += w * (H @ w2[e]^T + b2) ----------------
__global__ __launch_bounds__(256) void fc2_kernel(
    const unsigned short* __restrict__ Hbuf, const float* __restrict__ w2,
    const float* __restrict__ b2, const int* __restrict__ ptok,
    const float* __restrict__ pwv, const Ctrl* __restrict__ ctrl,
    float* __restrict__ y, int halfoff, int hcols)
{
  __shared__ short As[2][4096];
  __shared__ short Bs[2][4096];

  int m0 = blockIdx.y * 128;
  if ((unsigned)m0 >= ctrl->used_end) return;
  int e = 0;
  #pragma unroll
  for (int i = 1; i < 8; ++i) if ((unsigned)m0 >= ctrl->off[i]) e = i;

  int n0 = blockIdx.x * 128;   // within D
  int t = threadIdx.x;
  int r = t >> 1, sg = t & 1;
  const unsigned short* aSrc = Hbuf + (size_t)(m0 + r) * hcols + sg * 16;
  const float* bSrc = w2 + ((size_t)e * DDIM + n0 + r) * HDIM + halfoff + sg * 16;

  int wrA = r * 32;
  int ca = ((sg * 2)     ^ (r & 3)) << 3;
  int cb = ((sg * 2 + 1) ^ (r & 3)) << 3;

  int lane = t & 63, wid = t >> 6, wm = wid >> 1, wn = wid & 1;
  int kc = lane >> 4, rl = lane & 15;

  {
    const bf16x8* ap = (const bf16x8*)aSrc;
    const float4* bp = (const float4*)bSrc;
    bf16x8 a0 = ap[0], a1 = ap[1];
    float4 b0 = bp[0], b1v = bp[1], b2v = bp[2], b3 = bp[3];
    *(bf16x8*)&As[0][wrA + ca] = a0;
    *(bf16x8*)&As[0][wrA + cb] = a1;
    *(bf16x8*)&Bs[0][wrA + ca] = cvt8(b0, b1v);
    *(bf16x8*)&Bs[0][wrA + cb] = cvt8(b2v, b3);
  }
  __syncthreads();

  f32x4 acc[4][4] = {};
  const int NKL = hcols / 32;
  for (int kt = 0; kt < NKL; ++kt) {
    int cur = kt & 1, nxt = cur ^ 1;
    bool more = (kt + 1) < NKL;
    bf16x8 a0, a1;
    float4 b0, b1v, b2v, b3;
    if (more) {
      const bf16x8* ap = (const bf16x8*)(aSrc + (size_t)(kt + 1) * 32);
      const float4* bp = (const float4*)(bSrc + (kt + 1) * 32);
      a0 = ap[0]; a1 = ap[1];
      b0 = bp[0]; b1v = bp[1]; b2v = bp[2]; b3 = bp[3];
    }
    bf16x8 af[4], bfr[4];
    #pragma unroll
    for (int mi = 0; mi < 4; ++mi) {
      int rr = wm * 64 + mi * 16 + rl;
      af[mi] = *(bf16x8*)&As[cur][rr * 32 + ((kc ^ (rr & 3)) << 3)];
    }
    #pragma unroll
    for (int ni = 0; ni < 4; ++ni) {
      int rr = wn * 64 + ni * 16 + rl;
      bfr[ni] = *(bf16x8*)&Bs[cur][rr * 32 + ((kc ^ (rr & 3)) << 3)];
    }
    #pragma unroll
    for (int mi = 0; mi < 4; ++mi)
      #pragma unroll
      for (int ni = 0; ni < 4; ++ni)
        acc[mi][ni] = __builtin_amdgcn_mfma_f32_16x16x32_bf16(af[mi], bfr[ni], acc[mi][ni], 0, 0, 0);
    if (more) {
      *(bf16x8*)&As[nxt][wrA + ca] = a0;
      *(bf16x8*)&As[nxt][wrA + cb] = a1;
      *(bf16x8*)&Bs[nxt][wrA + ca] = cvt8(b0, b1v);
      *(bf16x8*)&Bs[nxt][wrA + cb] = cvt8(b2v, b3);
    }
    __syncthreads();
  }

  // epilogue: (+b2 on first chunk) * combine-weight, scatter-add into y
  #pragma unroll
  for (int mi = 0; mi < 4; ++mi) {
    #pragma unroll
    for (int rr2 = 0; rr2 < 4; ++rr2) {
      int grow = m0 + wm * 64 + mi * 16 + kc * 4 + rr2;
      int tok = ptok[grow];
      if (tok < 0) continue;
      float wgt = pwv[grow];
      float* yrow = y + (size_t)tok * DDIM;
      #pragma unroll
      for (int ni = 0; ni < 4; ++ni) {
        int col = n0 + wn * 64 + ni * 16 + rl;
        float v = acc[mi][ni][rr2];
        if (halfoff == 0) v += b2[e * DDIM + col];
        atomicAdd(&yrow[col], wgt * v);
      }
    }
  }
}

extern "C" void kernel_launch(void* const* d_in, const int* in_sizes, int n_in,
                              void* d_out, int out_size, void* d_ws, size_t ws_size,
                              hipStream_t stream) {
  (void)in_sizes; (void)n_in;
  const float* xp   = (const float*)d_in[0];
  const int*   mkp  = (const int*)d_in[1];
  const float* rwp  = (const float*)d_in[2];
  const float* w1p  = (const float*)d_in[3];
  const float* b1p  = (const float*)d_in[4];
  const float* w2p  = (const float*)d_in[5];
  const float* b2p  = (const float*)d_in[6];

  float* yp   = (float*)d_out;
  float* auxp = (float*)d_out + (out_size - 1);

  char* wsb = (char*)d_ws;
  Ctrl* ctrl = (Ctrl*)wsb;
  int*   top2i = (int*)(wsb + 1024);
  float* top2w = (float*)(wsb + 1024 + 65536);
  int*   ptok  = (int*)(wsb + 1024 + 131072);
  float* pwv   = (float*)(wsb + 1024 + 131072 + 69632);
  unsigned short* Hbuf = (unsigned short*)(wsb + 1048576);

  // choose H-chunk width so the bf16 H buffer fits the workspace (deterministic)
  int hcols = 4096;
  while (hcols > 128 && ws_size < 1048576 + (size_t)CAP * (size_t)hcols * 2) hcols >>= 1;
  int nchunks = HDIM / hcols;

  hipMemsetAsync(d_out, 0, (size_t)out_size * sizeof(float), stream);
  hipMemsetAsync(ctrl, 0, 256, stream);
  hipMemsetAsync(ptok, 0xFF, CAP * sizeof(int), stream);

  router_kernel<<<256, 256, 0, stream>>>(xp, mkp, rwp, ctrl, top2i, top2w);
  finalize_kernel<<<1, 1, 0, stream>>>(ctrl, auxp);
  scatter_kernel<<<NTOK / 256, 256, 0, stream>>>(mkp, ctrl, top2i, top2w, ptok, pwv);

  for (int c = 0; c < nchunks; ++c) {
    int hoff = c * hcols;
    fc1_kernel<<<dim3(hcols / 128, MT), 256, 0, stream>>>(xp, w1p, b1p, ptok, ctrl, Hbuf, hoff, hcols);
    fc2_kernel<<<dim3(DDIM / 128, MT), 256, 0, stream>>>(Hbuf, w2p, b2p, ptok, pwv, ctrl, yp, hoff, hcols);
  }
}

// Round 3
// 711.906 us; speedup vs baseline: 2.1580x; 1.1081x over previous
//
#include <hip/hip_runtime.h>
#include <hip/hip_bf16.h>

using bf16x8 = __attribute__((ext_vector_type(8))) short;
using f32x4  = __attribute__((ext_vector_type(4))) float;

#define NTOK 8192
#define DDIM 1024
#define NEXP 8
#define HDIM 4096
#define CAP  17408   // 16384 pairs + 8*128 padding
#define MT   136     // CAP / 128 M-tiles (worst case)

struct Ctrl {
  unsigned cnt[8];
  unsigned cursor[8];
  unsigned off[9];
  unsigned used_end;
  float imp[8];
  float loadsum[8];
  float validcnt;
};

typedef __attribute__((address_space(1))) unsigned GU;
typedef __attribute__((address_space(3))) unsigned LU;
// async global->LDS, 16B per lane; dest = wave-uniform base + lane*16 (HW rule)
__device__ __forceinline__ void gl_lds16(const unsigned short* g, short* l) {
  __builtin_amdgcn_global_load_lds((const GU*)(g), (LU*)(l), 16, 0, 0);
}

__device__ inline unsigned short f2bfu(float f) {
  __hip_bfloat16 h = __float2bfloat16(f);
  return *reinterpret_cast<unsigned short*>(&h);
}
__device__ inline bf16x8 cvt8(float4 a, float4 b) {
  bf16x8 v;
  v[0] = (short)f2bfu(a.x); v[1] = (short)f2bfu(a.y);
  v[2] = (short)f2bfu(a.z); v[3] = (short)f2bfu(a.w);
  v[4] = (short)f2bfu(b.x); v[5] = (short)f2bfu(b.y);
  v[6] = (short)f2bfu(b.z); v[7] = (short)f2bfu(b.w);
  return v;
}

// ---------------- Router: logits -> softmax -> top2 -> stats; also x -> bf16 ----------------
__global__ __launch_bounds__(256) void router_kernel(
    const float* __restrict__ x, const int* __restrict__ mask,
    const float* __restrict__ rw, Ctrl* __restrict__ ctrl,
    int* __restrict__ top2i, float* __restrict__ top2w,
    unsigned short* __restrict__ xb)
{
  __shared__ float s_imp[8];
  __shared__ float s_load[8];
  __shared__ unsigned s_cnt[8];
  __shared__ unsigned s_valid;
  if (threadIdx.x < 8) { s_imp[threadIdx.x] = 0.f; s_load[threadIdx.x] = 0.f; s_cnt[threadIdx.x] = 0u; }
  if (threadIdx.x == 0) s_valid = 0u;
  __syncthreads();

  int wid = threadIdx.x >> 6, lane = threadIdx.x & 63;

  for (int token = blockIdx.x * 4 + wid; token < NTOK; token += gridDim.x * 4) {
    const float* xr = x + (size_t)token * DDIM + lane * 16;
    float4 x0 = ((const float4*)xr)[0];
    float4 x1 = ((const float4*)xr)[1];
    float4 x2 = ((const float4*)xr)[2];
    float4 x3 = ((const float4*)xr)[3];

    // bf16 copy of x (consumed by fc1 via global_load_lds)
    unsigned short* xo = xb + (size_t)token * DDIM + lane * 16;
    *(bf16x8*)xo       = cvt8(x0, x1);
    *(bf16x8*)(xo + 8) = cvt8(x2, x3);

    float s[8];
    #pragma unroll
    for (int e = 0; e < 8; ++e) {
      const float* rp = rw + e * DDIM + lane * 16;
      float4 r0 = ((const float4*)rp)[0];
      float4 r1 = ((const float4*)rp)[1];
      float4 r2 = ((const float4*)rp)[2];
      float4 r3 = ((const float4*)rp)[3];
      float a = x0.x * r0.x;
      a = fmaf(x0.y, r0.y, a); a = fmaf(x0.z, r0.z, a); a = fmaf(x0.w, r0.w, a);
      a = fmaf(x1.x, r1.x, a); a = fmaf(x1.y, r1.y, a); a = fmaf(x1.z, r1.z, a); a = fmaf(x1.w, r1.w, a);
      a = fmaf(x2.x, r2.x, a); a = fmaf(x2.y, r2.y, a); a = fmaf(x2.z, r2.z, a); a = fmaf(x2.w, r2.w, a);
      a = fmaf(x3.x, r3.x, a); a = fmaf(x3.y, r3.y, a); a = fmaf(x3.z, r3.z, a); a = fmaf(x3.w, r3.w, a);
      s[e] = a;
    }
    #pragma unroll
    for (int e = 0; e < 8; ++e)
      #pragma unroll
      for (int o = 32; o; o >>= 1) s[e] += __shfl_xor(s[e], o);

    if (lane == 0) {
      float mx = s[0];
      #pragma unroll
      for (int e = 1; e < 8; ++e) mx = fmaxf(mx, s[e]);
      float p[8], sum = 0.f;
      #pragma unroll
      for (int e = 0; e < 8; ++e) { p[e] = __expf(s[e] - mx); sum += p[e]; }
      float inv = 1.0f / sum;
      #pragma unroll
      for (int e = 0; e < 8; ++e) p[e] *= inv;
      int i1 = 0;
      #pragma unroll
      for (int e = 1; e < 8; ++e) if (p[e] > p[i1]) i1 = e;
      int i2 = (i1 == 0) ? 1 : 0;
      #pragma unroll
      for (int e = 0; e < 8; ++e) if (e != i1 && p[e] > p[i2]) i2 = e;
      float denom = p[i1] + p[i2] + 1e-9f;
      top2i[2 * token] = i1;            top2i[2 * token + 1] = i2;
      top2w[2 * token] = p[i1] / denom; top2w[2 * token + 1] = p[i2] / denom;
      if (mask[token]) {
        #pragma unroll
        for (int e = 0; e < 8; ++e) atomicAdd(&s_imp[e], p[e]);   // LDS atomics
        atomicAdd(&s_load[i1], 1.0f);
        atomicAdd(&s_cnt[i1], 1u);
        atomicAdd(&s_cnt[i2], 1u);
        atomicAdd(&s_valid, 1u);
      }
    }
  }
  __syncthreads();
  if (threadIdx.x < 8) {
    if (s_imp[threadIdx.x] != 0.f)  atomicAdd(&ctrl->imp[threadIdx.x], s_imp[threadIdx.x]);
    if (s_load[threadIdx.x] != 0.f) atomicAdd(&ctrl->loadsum[threadIdx.x], s_load[threadIdx.x]);
    if (s_cnt[threadIdx.x])         atomicAdd(&ctrl->cnt[threadIdx.x], s_cnt[threadIdx.x]);
  }
  if (threadIdx.x == 0 && s_valid) atomicAdd(&ctrl->validcnt, (float)s_valid);
}

// ---------------- Offsets (128-aligned segments) + aux loss ----------------
__global__ void finalize_kernel(Ctrl* __restrict__ c, float* __restrict__ auxout)
{
  unsigned o = 0;
  for (int e = 0; e < 8; ++e) { c->off[e] = o; o += (c->cnt[e] + 127u) & ~127u; }
  c->off[8] = o;
  c->used_end = o;
  float cn = fmaxf(c->validcnt, 1.0f);
  float aux = 0.f;
  for (int e = 0; e < 8; ++e) aux += c->imp[e] * c->loadsum[e];
  auxout[0] = aux * 8.0f / (cn * cn);
}

// ---------------- Scatter pairs into per-expert segments ----------------
__global__ __launch_bounds__(256) void scatter_kernel(
    const int* __restrict__ mask, Ctrl* __restrict__ ctrl,
    const int* __restrict__ top2i, const float* __restrict__ top2w,
    int* __restrict__ ptok, float* __restrict__ pwv)
{
  __shared__ unsigned s_cnt[8], s_base[8], s_cur[8];
  if (threadIdx.x < 8) { s_cnt[threadIdx.x] = 0u; s_cur[threadIdx.x] = 0u; }
  __syncthreads();

  int token = blockIdx.x * 256 + threadIdx.x;
  int e0 = -1, e1 = -1; float w0 = 0.f, w1v = 0.f;
  bool valid = (token < NTOK) && mask[token];
  if (valid) {
    e0 = top2i[2 * token];     w0  = top2w[2 * token];
    e1 = top2i[2 * token + 1]; w1v = top2w[2 * token + 1];
    atomicAdd(&s_cnt[e0], 1u);
    atomicAdd(&s_cnt[e1], 1u);
  }
  __syncthreads();
  if (threadIdx.x < 8 && s_cnt[threadIdx.x])
    s_base[threadIdx.x] = ctrl->off[threadIdx.x] +
                          atomicAdd(&ctrl->cursor[threadIdx.x], s_cnt[threadIdx.x]);
  __syncthreads();
  if (valid) {
    unsigned p0 = atomicAdd(&s_cur[e0], 1u);
    unsigned row0 = s_base[e0] + p0;
    ptok[row0] = token; pwv[row0] = w0;
    unsigned p1 = atomicAdd(&s_cur[e1], 1u);
    unsigned row1 = s_base[e1] + p1;
    ptok[row1] = token; pwv[row1] = w1v;
  }
}

// ---------------- Weight chunk converters (fp32 -> bf16, each elem once) ----------------
__global__ __launch_bounds__(256) void convert_w1_kernel(
    const float* __restrict__ src, unsigned short* __restrict__ dst, int hoff, int HC)
{
  unsigned n = (unsigned)NEXP * HC * DDIM;
  unsigned step = gridDim.x * 256 * 8;
  unsigned chsz = (unsigned)HC * DDIM;
  for (unsigned flat = (blockIdx.x * 256 + threadIdx.x) * 8; flat < n; flat += step) {
    unsigned e = flat / chsz;
    const float* s = src + (size_t)flat + (size_t)e * (HDIM - HC) * DDIM + (size_t)hoff * DDIM;
    float4 v0 = ((const float4*)s)[0];
    float4 v1 = ((const float4*)s)[1];
    *(bf16x8*)&dst[flat] = cvt8(v0, v1);
  }
}

__global__ __launch_bounds__(256) void convert_w2_kernel(
    const float* __restrict__ src, unsigned short* __restrict__ dst, int hoff, int HC)
{
  unsigned n = (unsigned)NEXP * DDIM * HC;
  unsigned step = gridDim.x * 256 * 8;
  for (unsigned flat = (blockIdx.x * 256 + threadIdx.x) * 8; flat < n; flat += step) {
    unsigned row = flat / (unsigned)HC;              // e*DDIM + dout
    const float* s = src + (size_t)flat + (size_t)row * (HDIM - HC) + hoff;
    float4 v0 = ((const float4*)s)[0];
    float4 v1 = ((const float4*)s)[1];
    *(bf16x8*)&dst[flat] = cvt8(v0, v1);
  }
}

// ---------------- fc1: H = silu(gather(xb) @ w1b^T + b1) -> bf16 (m97 structure) ----------------
__global__ __launch_bounds__(256) void fc1_kernel(
    const unsigned short* __restrict__ xb, const unsigned short* __restrict__ w1b,
    const float* __restrict__ b1, const int* __restrict__ ptok,
    const Ctrl* __restrict__ ctrl, unsigned short* __restrict__ Hbuf,
    int hoff, int HC)
{
  __shared__ __align__(16) short As[4096];   // 128 rows x 32 bf16 (64B rows)
  __shared__ __align__(16) short Bs[4096];

  // XCD-aware swizzle (nwg % 8 == 0)
  int nwg = gridDim.x * gridDim.y;
  int id  = blockIdx.y * gridDim.x + blockIdx.x;
  int cpx = nwg >> 3;
  int swz = (id & 7) * cpx + (id >> 3);
  int bx = swz % gridDim.x, by = swz / gridDim.x;

  int m0 = by * 128;
  if ((unsigned)m0 >= ctrl->used_end) return;
  int e = 0;
  #pragma unroll
  for (int i = 1; i < 8; ++i) if ((unsigned)m0 >= ctrl->off[i]) e = i;

  int n0 = bx * 128;
  int t = threadIdx.x, w = t >> 6, l = t & 63;
  int lr = l >> 2, lc = l & 3;
  // rule-21: linear LDS dest; source chunk pre-XOR'd; read chunk XOR'd the same way
  int srcc = (lc ^ ((l >> 3) & 3)) * 8;       // element offset of the 16B chunk this lane loads

  int ra0 = w * 16 + lr, ra1 = 64 + w * 16 + lr;
  int t0 = ptok[m0 + ra0]; if (t0 < 0) t0 = 0;
  int t1 = ptok[m0 + ra1]; if (t1 < 0) t1 = 0;
  const unsigned short* a0p = xb + (size_t)t0 * DDIM + srcc;
  const unsigned short* a1p = xb + (size_t)t1 * DDIM + srcc;
  const unsigned short* b0p = w1b + ((size_t)e * HC + n0 + ra0) * DDIM + srcc;
  const unsigned short* b1p = w1b + ((size_t)e * HC + n0 + ra1) * DDIM + srcc;
  short* As0 = &As[w * 512];          short* As1 = &As[2048 + w * 512];
  short* Bs0 = &Bs[w * 512];          short* Bs1 = &Bs[2048 + w * 512];

  int wm = w >> 1, wn = w & 1, kc = l >> 4, rl = l & 15;
  int rdc = ((kc ^ ((rl >> 1) & 3)) << 3);    // swizzled read chunk (per-thread const)

  f32x4 acc[4][4] = {};
  for (int kt = 0; kt < DDIM / 32; ++kt) {
    gl_lds16(a0p + kt * 32, As0);
    gl_lds16(a1p + kt * 32, As1);
    gl_lds16(b0p + kt * 32, Bs0);
    gl_lds16(b1p + kt * 32, Bs1);
    __syncthreads();                  // compiler drains vmcnt before s_barrier
    bf16x8 af[4], bf[4];
    #pragma unroll
    for (int mi = 0; mi < 4; ++mi)
      af[mi] = *(const bf16x8*)&As[(wm * 64 + mi * 16 + rl) * 32 + rdc];
    #pragma unroll
    for (int ni = 0; ni < 4; ++ni)
      bf[ni] = *(const bf16x8*)&Bs[(wn * 64 + ni * 16 + rl) * 32 + rdc];
    #pragma unroll
    for (int mi = 0; mi < 4; ++mi)
      #pragma unroll
      for (int ni = 0; ni < 4; ++ni)
        acc[mi][ni] = __builtin_amdgcn_mfma_f32_16x16x32_bf16(af[mi], bf[ni], acc[mi][ni], 0, 0, 0);
    __syncthreads();
  }

  #pragma unroll
  for (int mi = 0; mi < 4; ++mi) {
    #pragma unroll
    for (int rr2 = 0; rr2 < 4; ++rr2) {
      int grow = m0 + wm * 64 + mi * 16 + kc * 4 + rr2;
      size_t base = (size_t)grow * HC;
      #pragma unroll
      for (int ni = 0; ni < 4; ++ni) {
        int col = n0 + wn * 64 + ni * 16 + rl;
        float v = acc[mi][ni][rr2] + b1[e * HDIM + hoff + col];
        v = v / (1.0f + __expf(-v));
        Hbuf[base + col] = f2bfu(v);
      }
    }
  }
}

// ---------------- fc2: y += w * (Hbuf @ w2b^T + b2) (m97 structure) ----------------
__global__ __launch_bounds__(256) void fc2_kernel(
    const unsigned short* __restrict__ Hbuf, const unsigned short* __restrict__ w2b,
    const float* __restrict__ b2, const int* __restrict__ ptok,
    const float* __restrict__ pwv, const Ctrl* __restrict__ ctrl,
    float* __restrict__ y, int hoff, int HC)
{
  __shared__ __align__(16) short As[4096];
  __shared__ __align__(16) short Bs[4096];

  int nwg = gridDim.x * gridDim.y;
  int id  = blockIdx.y * gridDim.x + blockIdx.x;
  int cpx = nwg >> 3;
  int swz = (id & 7) * cpx + (id >> 3);
  int bx = swz % gridDim.x, by = swz / gridDim.x;

  int m0 = by * 128;
  if ((unsigned)m0 >= ctrl->used_end) return;
  int e = 0;
  #pragma unroll
  for (int i = 1; i < 8; ++i) if ((unsigned)m0 >= ctrl->off[i]) e = i;

  int n0 = bx * 128;
  int t = threadIdx.x, w = t >> 6, l = t & 63;
  int lr = l >> 2, lc = l & 3;
  int srcc = (lc ^ ((l >> 3) & 3)) * 8;

  int ra0 = w * 16 + lr, ra1 = 64 + w * 16 + lr;
  const unsigned short* a0p = Hbuf + (size_t)(m0 + ra0) * HC + srcc;
  const unsigned short* a1p = Hbuf + (size_t)(m0 + ra1) * HC + srcc;
  const unsigned short* b0p = w2b + ((size_t)e * DDIM + n0 + ra0) * HC + srcc;
  const unsigned short* b1p = w2b + ((size_t)e * DDIM + n0 + ra1) * HC + srcc;
  short* As0 = &As[w * 512];          short* As1 = &As[2048 + w * 512];
  short* Bs0 = &Bs[w * 512];          short* Bs1 = &Bs[2048 + w * 512];

  int wm = w >> 1, wn = w & 1, kc = l >> 4, rl = l & 15;
  int rdc = ((kc ^ ((rl >> 1) & 3)) << 3);

  f32x4 acc[4][4] = {};
  const int NKL = HC / 32;
  for (int kt = 0; kt < NKL; ++kt) {
    gl_lds16(a0p + kt * 32, As0);
    gl_lds16(a1p + kt * 32, As1);
    gl_lds16(b0p + kt * 32, Bs0);
    gl_lds16(b1p + kt * 32, Bs1);
    __syncthreads();
    bf16x8 af[4], bf[4];
    #pragma unroll
    for (int mi = 0; mi < 4; ++mi)
      af[mi] = *(const bf16x8*)&As[(wm * 64 + mi * 16 + rl) * 32 + rdc];
    #pragma unroll
    for (int ni = 0; ni < 4; ++ni)
      bf[ni] = *(const bf16x8*)&Bs[(wn * 64 + ni * 16 + rl) * 32 + rdc];
    #pragma unroll
    for (int mi = 0; mi < 4; ++mi)
      #pragma unroll
      for (int ni = 0; ni < 4; ++ni)
        acc[mi][ni] = __builtin_amdgcn_mfma_f32_16x16x32_bf16(af[mi], bf[ni], acc[mi][ni], 0, 0, 0);
    __syncthreads();
  }

  #pragma unroll
  for (int mi = 0; mi < 4; ++mi) {
    #pragma unroll
    for (int rr2 = 0; rr2 < 4; ++rr2) {
      int grow = m0 + wm * 64 + mi * 16 + kc * 4 + rr2;
      int tok = ptok[grow];
      if (tok < 0) continue;
      float wgt = pwv[grow];
      float* yrow = y + (size_t)tok * DDIM;
      #pragma unroll
      for (int ni = 0; ni < 4; ++ni) {
        int col = n0 + wn * 64 + ni * 16 + rl;
        float v = acc[mi][ni][rr2];
        if (hoff == 0) v += b2[e * DDIM + col];
        atomicAdd(&yrow[col], wgt * v);
      }
    }
  }
}

extern "C" void kernel_launch(void* const* d_in, const int* in_sizes, int n_in,
                              void* d_out, int out_size, void* d_ws, size_t ws_size,
                              hipStream_t stream) {
  (void)in_sizes; (void)n_in;
  const float* xp   = (const float*)d_in[0];
  const int*   mkp  = (const int*)d_in[1];
  const float* rwp  = (const float*)d_in[2];
  const float* w1p  = (const float*)d_in[3];
  const float* b1p  = (const float*)d_in[4];
  const float* w2p  = (const float*)d_in[5];
  const float* b2p  = (const float*)d_in[6];

  float* yp   = (float*)d_out;
  float* auxp = (float*)d_out + (out_size - 1);

  char* wsb = (char*)d_ws;
  Ctrl* ctrl = (Ctrl*)wsb;
  int*   top2i = (int*)(wsb + 1024);
  float* top2w = (float*)(wsb + 1024 + 65536);
  int*   ptok  = (int*)(wsb + 132096);
  float* pwv   = (float*)(wsb + 201728);
  unsigned short* xb   = (unsigned short*)(wsb + 1048576);
  unsigned short* Wbuf = (unsigned short*)(wsb + 17825792);   // 8*HC*1024 bf16 (w1b or w2b chunk)

  // HC ladder: peak ws = 17825792 + 16384*HC (Wbuf) + 34816*HC (Hbuf)
  int HC = 4096;
  while (HC > 128 && ws_size < 17825792ull + 51200ull * (unsigned long long)HC) HC >>= 1;
  int nch = HDIM / HC;
  unsigned short* Hbuf = (unsigned short*)(wsb + 17825792 + (size_t)16384 * HC);

  hipMemsetAsync(d_out, 0, (size_t)out_size * sizeof(float), stream);
  hipMemsetAsync(ctrl, 0, 256, stream);
  hipMemsetAsync(ptok, 0xFF, CAP * sizeof(int), stream);

  router_kernel<<<256, 256, 0, stream>>>(xp, mkp, rwp, ctrl, top2i, top2w, xb);
  finalize_kernel<<<1, 1, 0, stream>>>(ctrl, auxp);
  scatter_kernel<<<NTOK / 256, 256, 0, stream>>>(mkp, ctrl, top2i, top2w, ptok, pwv);

  for (int c = 0; c < nch; ++c) {
    int hoff = c * HC;
    convert_w1_kernel<<<2048, 256, 0, stream>>>(w1p, Wbuf, hoff, HC);
    fc1_kernel<<<dim3(HC / 128, MT), 256, 0, stream>>>(xb, Wbuf, b1p, ptok, ctrl, Hbuf, hoff, HC);
    convert_w2_kernel<<<2048, 256, 0, stream>>>(w2p, Wbuf, hoff, HC);
    fc2_kernel<<<dim3(DDIM / 128, MT), 256, 0, stream>>>(Hbuf, Wbuf, b2p, ptok, pwv, ctrl, yp, hoff, HC);
  }
}